// Round 8
// baseline (772.879 us; speedup 1.0000x reference)
//
#include <hip/hip_runtime.h>
#include <hip/hip_bf16.h>
#include <math.h>

#define F_IN 128
#define HD   64    // H*D layer1
#define NH   8
#define DH   8
#define NC   7     // classes

__device__ __forceinline__ float lrelu(float e) { return fmaxf(e, 0.2f * e); }
__device__ __forceinline__ ushort f2bf(float f) {
    unsigned u = __float_as_uint(f);
    unsigned rounded = u + 0x7FFF + ((u >> 16) & 1);
    return (ushort)(rounded >> 16);
}

// ---------------- K1: h1b = bf16(x@W1), a_src1/a_dst1 = (h1*att).sum(-1) -----
// 8 rows per wave; weight-stationary in LDS; x loads are wave-uniform
// broadcasts. Standalone (R7's gemm+hist fusion regressed: hist blocks
// inherited the 33KB LDS allocation and crushed occupancy for both).
__global__ __launch_bounds__(256) void k_gemm1(
    const float* __restrict__ x, const float* __restrict__ W1,
    const float* __restrict__ att_src, const float* __restrict__ att_dst,
    ushort* __restrict__ h1b, float* __restrict__ a_src, float* __restrict__ a_dst,
    int N)
{
    __shared__ float sW[F_IN * HD];      // 32 KB
    __shared__ float sAs[HD], sAd[HD];
    int t = threadIdx.x;
    for (int i = t; i < F_IN * HD; i += 256) sW[i] = W1[i];
    if (t < HD) { sAs[t] = att_src[t]; sAd[t] = att_dst[t]; }
    __syncthreads();

    int lane = t & 63;
    int wave = t >> 6;
    int base = blockIdx.x * 64 + wave * 16;

    for (int it = 0; it < 2; ++it) {
        int r0 = base + it * 8;
        if (r0 >= N) break;
        int nr = N - r0; if (nr > 8) nr = 8;
        float acc[8];
        #pragma unroll
        for (int r = 0; r < 8; ++r) acc[r] = 0.f;

        if (nr == 8) {
            for (int k4 = 0; k4 < F_IN / 4; ++k4) {
                float4 xv[8];
                #pragma unroll
                for (int r = 0; r < 8; ++r)
                    xv[r] = *(const float4*)(x + (size_t)(r0 + r) * F_IN + k4 * 4);
                #pragma unroll
                for (int kk = 0; kk < 4; ++kk) {
                    float sw = sW[(k4 * 4 + kk) * HD + lane];
                    acc[0] += ((const float*)&xv[0])[kk] * sw;
                    acc[1] += ((const float*)&xv[1])[kk] * sw;
                    acc[2] += ((const float*)&xv[2])[kk] * sw;
                    acc[3] += ((const float*)&xv[3])[kk] * sw;
                    acc[4] += ((const float*)&xv[4])[kk] * sw;
                    acc[5] += ((const float*)&xv[5])[kk] * sw;
                    acc[6] += ((const float*)&xv[6])[kk] * sw;
                    acc[7] += ((const float*)&xv[7])[kk] * sw;
                }
            }
        } else {
            #pragma unroll
            for (int r = 0; r < 8; ++r) {
                if (r < nr) {
                    const float4* xr4 = (const float4*)(x + (size_t)(r0 + r) * F_IN);
                    float a = 0.f;
                    for (int k4 = 0; k4 < F_IN / 4; ++k4) {
                        float4 q = xr4[k4];
                        a += q.x * sW[(k4 * 4 + 0) * HD + lane];
                        a += q.y * sW[(k4 * 4 + 1) * HD + lane];
                        a += q.z * sW[(k4 * 4 + 2) * HD + lane];
                        a += q.w * sW[(k4 * 4 + 3) * HD + lane];
                    }
                    acc[r] = a;
                }
            }
        }
        #pragma unroll
        for (int r = 0; r < 8; ++r) {
            if (r < nr) {
                int row = r0 + r;
                float a = acc[r];
                h1b[(size_t)row * HD + lane] = f2bf(a);
                float vs = a * sAs[lane];
                float vd = a * sAd[lane];
                #pragma unroll
                for (int o = 4; o > 0; o >>= 1) {
                    vs += __shfl_down(vs, o, 8);
                    vd += __shfl_down(vd, o, 8);
                }
                if ((lane & 7) == 0) {
                    int h = lane >> 3;
                    a_src[row * NH + h] = vs;
                    a_dst[row * NH + h] = vd;
                }
            }
        }
    }
}

// ---------------- CSR build ---------------------------------------------------
__global__ __launch_bounds__(256) void k_hist(
    const int* __restrict__ dst, int* __restrict__ deg, int* __restrict__ rank,
    long E)
{
    long i = (long)blockIdx.x * 256 + threadIdx.x;
    if (i < E) rank[i] = atomicAdd(&deg[dst[i]], 1);
}

__global__ __launch_bounds__(256) void k_bsum(
    const int* __restrict__ deg, int* __restrict__ bsum, int N)
{
    __shared__ int s[256];
    int t = threadIdx.x;
    int i = blockIdx.x * 256 + t;
    s[t] = (i < N) ? deg[i] : 0;
    __syncthreads();
    #pragma unroll
    for (int o = 128; o > 0; o >>= 1) {
        if (t < o) s[t] += s[t + o];
        __syncthreads();
    }
    if (t == 0) bsum[blockIdx.x] = s[0];
}

__global__ __launch_bounds__(512) void k_scan_bsum(
    const int* __restrict__ bsum, int* __restrict__ bexc, int NB)
{
    __shared__ int s[512];
    int t = threadIdx.x;
    s[t] = (t < NB) ? bsum[t] : 0;
    __syncthreads();
    for (int o = 1; o < 512; o <<= 1) {
        int v = (t >= o) ? s[t - o] : 0;
        __syncthreads();
        s[t] += v;
        __syncthreads();
    }
    if (t < NB) bexc[t] = (t == 0) ? 0 : s[t - 1];
}

__global__ __launch_bounds__(256) void k_rowptr(
    const int* __restrict__ deg, const int* __restrict__ bexc,
    int* __restrict__ rowptr, int N, int Etot)
{
    __shared__ int s[256];
    int t = threadIdx.x;
    int i = blockIdx.x * 256 + t;
    int v = (i < N) ? deg[i] : 0;
    s[t] = v;
    __syncthreads();
    for (int o = 1; o < 256; o <<= 1) {
        int u = (t >= o) ? s[t - o] : 0;
        __syncthreads();
        s[t] += u;
        __syncthreads();
    }
    if (i < N) rowptr[i] = bexc[blockIdx.x] + s[t] - v;  // exclusive
    if (i == 0) rowptr[N] = Etot;
}

__global__ __launch_bounds__(256) void k_fill(
    const int* __restrict__ src, const int* __restrict__ dst,
    const int* __restrict__ rank, const int* __restrict__ rowptr,
    int* __restrict__ csr, long E)
{
    long i = (long)blockIdx.x * 256 + threadIdx.x;
    if (i >= E) return;
    csr[rowptr[dst[i]] + rank[i]] = src[i];
}

// ---------------- K-gather1 v5: wave per dst, lane=(e,h), NO loop shuffles ---
// Head h owns dwords h*4..h*4+3 of the 32-dword bf16 row, so lane (e,h) loads
// its edge's 4 consecutive dwords and scales by its OWN weight. Per 8-edge
// chunk: 3 VMEM + ~27 VALU, zero LDS ops. Reduction once per row in epilogue.
__global__ __launch_bounds__(256) void k_gather1(
    const int* __restrict__ rowptr, const int* __restrict__ csr,
    const ushort* __restrict__ h1b, const float* __restrict__ a_src,
    const float* __restrict__ a_dst, float* __restrict__ agg, int N)
{
    const uint* __restrict__ h1u = (const uint*)h1b;
    int wave = threadIdx.x >> 6, lane = threadIdx.x & 63;
    int d = blockIdx.x * 4 + wave;
    if (d >= N) return;
    int e = lane >> 3;           // edge slot
    int h = lane & 7;            // head; channels 8h..8h+7 = dwords 4h..4h+3

    float adst = a_dst[d * NH + h];
    float ws = __expf(lrelu(a_src[d * NH + h] + adst));   // self-loop weight
    float wsum = (e == 0) ? ws : 0.f;

    float ax0 = 0.f, ay0 = 0.f, ax1 = 0.f, ay1 = 0.f;
    float ax2 = 0.f, ay2 = 0.f, ax3 = 0.f, ay3 = 0.f;
    if (e == 0) {
        size_t b = (size_t)d * 32 + h * 4;
        uint u0 = h1u[b], u1 = h1u[b + 1], u2 = h1u[b + 2], u3 = h1u[b + 3];
        ax0 = ws * __uint_as_float(u0 << 16); ay0 = ws * __uint_as_float(u0 & 0xFFFF0000u);
        ax1 = ws * __uint_as_float(u1 << 16); ay1 = ws * __uint_as_float(u1 & 0xFFFF0000u);
        ax2 = ws * __uint_as_float(u2 << 16); ay2 = ws * __uint_as_float(u2 & 0xFFFF0000u);
        ax3 = ws * __uint_as_float(u3 << 16); ay3 = ws * __uint_as_float(u3 & 0xFFFF0000u);
    }

    int jb = rowptr[d], je = rowptr[d + 1];
    // software pipeline: next chunk's csr + a_src prefetched during accumulate
    int  idx0   = jb + e;
    bool v_cur  = idx0 < je;
    int  sl_cur = v_cur ? csr[idx0] : d;
    float as_cur = a_src[sl_cur * NH + h];

    for (int j0 = jb; j0 < je; j0 += 8) {
        int  idxn  = j0 + 8 + e;
        bool v_n   = idxn < je;
        int  sl_n  = v_n ? csr[idxn] : d;
        float as_n = a_src[sl_n * NH + h];

        float w = v_cur ? __expf(lrelu(as_cur + adst)) : 0.f;
        wsum += w;
        size_t b = (size_t)sl_cur * 32 + h * 4;
        uint u0 = h1u[b], u1 = h1u[b + 1], u2 = h1u[b + 2], u3 = h1u[b + 3];
        ax0 += w * __uint_as_float(u0 << 16); ay0 += w * __uint_as_float(u0 & 0xFFFF0000u);
        ax1 += w * __uint_as_float(u1 << 16); ay1 += w * __uint_as_float(u1 & 0xFFFF0000u);
        ax2 += w * __uint_as_float(u2 << 16); ay2 += w * __uint_as_float(u2 & 0xFFFF0000u);
        ax3 += w * __uint_as_float(u3 << 16); ay3 += w * __uint_as_float(u3 & 0xFFFF0000u);

        sl_cur = sl_n; as_cur = as_n; v_cur = v_n;
    }

    // epilogue: reduce over edge slots (xor bits 3..5 keeps h fixed)
    #pragma unroll
    for (int o = 8; o <= 32; o <<= 1) {
        wsum += __shfl_xor(wsum, o, 64);
        ax0 += __shfl_xor(ax0, o, 64); ay0 += __shfl_xor(ay0, o, 64);
        ax1 += __shfl_xor(ax1, o, 64); ay1 += __shfl_xor(ay1, o, 64);
        ax2 += __shfl_xor(ax2, o, 64); ay2 += __shfl_xor(ay2, o, 64);
        ax3 += __shfl_xor(ax3, o, 64); ay3 += __shfl_xor(ay3, o, 64);
    }
    if (e == 0) {
        float winv = 1.f / (wsum + 1e-16f);
        float* op = agg + (size_t)d * HD + h * 8;
        *(float4*)(op)     = make_float4(ax0 * winv, ay0 * winv, ax1 * winv, ay1 * winv);
        *(float4*)(op + 4) = make_float4(ax2 * winv, ay2 * winv, ax3 * winv, ay3 * winv);
    }
}

// ------- K4: emb = agg1+b1 (OUT0); x2 = elu(emb); h2p = x2@W2; a_*2 ----------
__global__ __launch_bounds__(256) void k_node2(
    const float* __restrict__ agg1, const float* __restrict__ b1,
    const float* __restrict__ W2, const float* __restrict__ att_s2,
    const float* __restrict__ att_d2, float* __restrict__ emb_out,
    float* __restrict__ h2p, float* __restrict__ a_src2, float* __restrict__ a_dst2,
    int N)
{
    __shared__ float sW[HD * NC];
    __shared__ float sb[HD];
    __shared__ float sas[NC], sad[NC];
    int t = threadIdx.x;
    for (int i = t; i < HD * NC; i += 256) sW[i] = W2[i];
    if (t < HD) sb[t] = b1[t];
    if (t < NC) { sas[t] = att_s2[t]; sad[t] = att_d2[t]; }
    __syncthreads();
    int n = blockIdx.x * 256 + t;
    if (n >= N) return;
    const float* ag = agg1 + (size_t)n * HD;
    float* eo = emb_out + (size_t)n * HD;
    float acc[NC];
    #pragma unroll
    for (int c = 0; c < NC; ++c) acc[c] = 0.f;
    #pragma unroll 8
    for (int k = 0; k < HD; ++k) {
        float v = ag[k] + sb[k];
        eo[k] = v;
        float xv = v > 0.f ? v : expm1f(v);   // jax.nn.elu
        #pragma unroll
        for (int c = 0; c < NC; ++c) acc[c] += xv * sW[k * NC + c];
    }
    float as = 0.f, ad = 0.f;
    float* hp = h2p + (size_t)n * 8;
    #pragma unroll
    for (int c = 0; c < NC; ++c) {
        hp[c] = acc[c];
        as += acc[c] * sas[c];
        ad += acc[c] * sad[c];
    }
    hp[7] = 0.f;
    a_src2[n] = as;
    a_dst2[n] = ad;
}

// ------- K-gather2: WAVE per dst; lane = edge-slot*8 + channel; pipelined ----
__global__ __launch_bounds__(256) void k_gather2(
    const int* __restrict__ rowptr, const int* __restrict__ csr,
    const float* __restrict__ h2p, const float* __restrict__ a_src2,
    const float* __restrict__ a_dst2, const float* __restrict__ b2,
    float* __restrict__ out, int N)
{
    int t = threadIdx.x;
    int wave = t >> 6, lane = t & 63;
    int g = lane >> 3;           // edge slot 0..7
    int c = lane & 7;            // channel (7 = pad)
    int n = blockIdx.x * 4 + wave;
    if (n >= N) return;
    float ad = a_dst2[n];
    float w = __expf(lrelu(a_src2[n] + ad));   // self-loop
    float acc  = (g == 0) ? w * h2p[(size_t)n * 8 + c] : 0.f;
    float wsum = (g == 0) ? w : 0.f;
    int jb = rowptr[n], je = rowptr[n + 1];

    int  idx0  = jb + g;
    bool v_cur = idx0 < je;
    int  s_cur = v_cur ? csr[idx0] : n;

    for (int j = jb; j < je; j += 8) {
        int  idxn  = j + 8 + g;
        bool v_n   = idxn < je;
        int  s_n   = v_n ? csr[idxn] : n;
        float ww = v_cur ? __expf(lrelu(a_src2[s_cur] + ad)) : 0.f;
        acc += ww * h2p[(size_t)s_cur * 8 + c];
        wsum += ww;
        s_cur = s_n; v_cur = v_n;
    }
    #pragma unroll
    for (int o = 32; o >= 8; o >>= 1) {
        acc  += __shfl_xor(acc, o, 64);
        wsum += __shfl_xor(wsum, o, 64);
    }
    float l = (c < NC) ? (acc / (wsum + 1e-16f) + b2[c]) : -1e30f;
    float m = l;
    #pragma unroll
    for (int o = 4; o > 0; o >>= 1) m = fmaxf(m, __shfl_xor(m, o, 8));
    float ex = (c < NC) ? __expf(l - m) : 0.f;
    float s8 = ex;
    #pragma unroll
    for (int o = 4; o > 0; o >>= 1) s8 += __shfl_xor(s8, o, 8);
    if (g == 0 && c < NC) out[(size_t)n * NC + c] = l - m - logf(s8);
}

extern "C" void kernel_launch(void* const* d_in, const int* in_sizes, int n_in,
                              void* d_out, int out_size, void* d_ws, size_t ws_size,
                              hipStream_t stream)
{
    const float* x       = (const float*)d_in[0];
    const int*   ei      = (const int*)d_in[1];
    const float* W1      = (const float*)d_in[2];
    const float* att_s1  = (const float*)d_in[3];
    const float* att_d1  = (const float*)d_in[4];
    const float* b1      = (const float*)d_in[5];
    const float* W2      = (const float*)d_in[6];
    const float* att_s2  = (const float*)d_in[7];
    const float* att_d2  = (const float*)d_in[8];
    const float* b2      = (const float*)d_in[9];

    const int  N = in_sizes[0] / F_IN;
    const long E = (long)in_sizes[1] / 2;
    const int* src = ei;
    const int* dst = ei + E;

    const int Npad  = (N + 3) & ~3;
    const int Np1p  = (N + 4) & ~3;
    const long Epad = (E + 3) & ~3;

    // ---- workspace layout ----
    int* deg    = (int*)d_ws;                 // Npad   (zeroed)
    int* rowptr = deg + Npad;                 // N+1
    int* bexc   = rowptr + Np1p;              // 512
    int* bsum   = bexc + 512;                 // 512
    int* csr    = bsum + 512;                 // E
    ushort* h1b   = (ushort*)(csr + Epad);    // Npad*64 bf16
    float* a_src1 = (float*)(h1b + (size_t)Npad * HD); // N*8
    float* a_dst1 = a_src1 + (size_t)N * NH;  // N*8
    float* agg1   = a_dst1 + (size_t)N * NH;  // N*64
    float* h2p    = agg1 + (size_t)N * HD;    // N*8 (padded NC->8)
    float* a_src2 = h2p + (size_t)N * 8;      // Npad
    float* a_dst2 = a_src2 + Npad;            // Npad
    float* wsend  = a_dst2 + Npad;
    // rank[E] aliases agg1's space (dead before k_gather1 writes agg1)
    int* rank = (E <= (long)N * HD) ? (int*)agg1 : (int*)wsend;

    hipMemsetAsync(deg, 0, (size_t)Npad * sizeof(int), stream);

    const int NB = (N + 255) / 256;
    dim3 b256(256);

    k_gemm1<<<dim3((N + 63) / 64), b256, 0, stream>>>(x, W1, att_s1, att_d1,
                                                      h1b, a_src1, a_dst1, N);
    // CSR build
    k_hist<<<dim3((unsigned)((E + 255) / 256)), b256, 0, stream>>>(dst, deg, rank, E);
    k_bsum<<<dim3(NB), b256, 0, stream>>>(deg, bsum, N);
    k_scan_bsum<<<dim3(1), dim3(512), 0, stream>>>(bsum, bexc, NB);
    k_rowptr<<<dim3(NB), b256, 0, stream>>>(deg, bexc, rowptr, N, (int)E);
    k_fill<<<dim3((unsigned)((E + 255) / 256)), b256, 0, stream>>>(
        src, dst, rank, rowptr, csr, E);

    // Layer 1 aggregate
    k_gather1<<<dim3((N + 3) / 4), b256, 0, stream>>>(
        rowptr, csr, h1b, a_src1, a_dst1, agg1, N);

    // emb output + layer-2 prologue
    float* emb = (float*)d_out;               // N*64
    float* lsm = emb + (size_t)N * HD;        // N*7
    k_node2<<<dim3(NB), b256, 0, stream>>>(
        agg1, b1, W2, att_s2, att_d2, emb, h2p, a_src2, a_dst2, N);

    // Layer 2 aggregate + fused log_softmax
    k_gather2<<<dim3((N + 3) / 4), b256, 0, stream>>>(
        rowptr, csr, h2p, a_src2, a_dst2, b2, lsm, N);
}